// Round 1
// baseline (972.076 us; speedup 1.0000x reference)
//
#include <hip/hip_runtime.h>
#include <math.h>

typedef unsigned short u16;
typedef unsigned int u32;
typedef __attribute__((ext_vector_type(8))) short frag_ab;   // 8 bf16 (4 VGPRs)
typedef __attribute__((ext_vector_type(4))) float floatx4;   // 4 fp32 acc

__device__ __forceinline__ u16 f2bf(float f){   // RNE fp32 -> bf16
  u32 u; __builtin_memcpy(&u, &f, 4);
  u32 r = u + 0x7fffu + ((u >> 16) & 1u);
  return (u16)(r >> 16);
}
__device__ __forceinline__ float bf2f(u16 h){
  u32 u = ((u32)h) << 16;
  float f; __builtin_memcpy(&f, &u, 4); return f;
}
// pack two fp32 -> two bf16 (truncation) in ONE v_perm: low u16 = trunc(lo), high = trunc(hi)
__device__ __forceinline__ u32 pack2(float hi, float lo){
  u32 a, b; __builtin_memcpy(&a, &hi, 4); __builtin_memcpy(&b, &lo, 4);
  return __builtin_amdgcn_perm(a, b, 0x07060302u);
}

// async global->LDS, 16B per lane. LDS dest must be wave-uniform base + lane*16,
// which our linear [row][k] layout with 4 lanes/row * 16B satisfies (dest = base + tid*16).
__device__ __forceinline__ void gload16(u16* l, const u16* g){
  __builtin_amdgcn_global_load_lds(
      (const __attribute__((address_space(1))) void*)g,
      (__attribute__((address_space(3))) void*)l, 16, 0, 0);
}

// ---- K1: per-row LN stats (fp32 in). XB: also write x as bf16 (RNE). ----
// block = 256 = D/8, grid = M
template<bool XB>
__global__ __launch_bounds__(256) void ln_stats_kernel(
    const float* __restrict__ x, float2* __restrict__ stats,
    u16* __restrict__ xb, int D)
{
  const int row = blockIdx.x;
  const int tid = threadIdx.x;
  const float* xr = x + (size_t)row * D + tid * 8;
  float4 q0 = *(const float4*)xr;
  float4 q1 = *(const float4*)(xr + 4);
  float f[8] = {q0.x,q0.y,q0.z,q0.w,q1.x,q1.y,q1.z,q1.w};
  float s = 0.f, q = 0.f;
#pragma unroll
  for (int i = 0; i < 8; ++i){ s += f[i]; q += f[i]*f[i]; }
#pragma unroll
  for (int o = 32; o > 0; o >>= 1){ s += __shfl_xor(s, o); q += __shfl_xor(q, o); }
  __shared__ float red[2][4];
  const int lane = tid & 63, w = tid >> 6;
  if (lane == 0){ red[0][w] = s; red[1][w] = q; }
  __syncthreads();
  if (XB){
    u16 ov[8];
#pragma unroll
    for (int i = 0; i < 8; ++i) ov[i] = f2bf(f[i]);
    *(uint4*)(xb + (size_t)row * D + tid * 8) = *(const uint4*)ov;
  }
  if (tid == 0){
    float S = red[0][0] + red[0][1] + red[0][2] + red[0][3];
    float Q = red[1][0] + red[1][1] + red[1][2] + red[1][3];
    float invD = 1.0f / (float)D;
    float mu  = S * invD;
    float var = Q * invD - mu * mu;
    stats[row] = make_float2(mu, rsqrtf(var + 1e-5f));
  }
}

// ---- K2: u[n]=0, c[n]=bias[n] ----
__global__ __launch_bounds__(256) void init_uc_kernel(
    const float* __restrict__ b, float* __restrict__ u, float* __restrict__ c, int H)
{
  int t = blockIdx.x * 256 + threadIdx.x;
  if (t < H){ u[t] = 0.f; c[t] = b[t]; }
}

// ---- K3: u[n] += sum_k g[k]W[k,n];  c[n] += sum_k beta[k]W[k,n]  (all fp32) ----
__global__ __launch_bounds__(256) void colsum_kernel(
    const float* __restrict__ W, const float* __restrict__ g, const float* __restrict__ beta,
    float* __restrict__ u, float* __restrict__ c, int D, int H, int KS)
{
  const int n  = blockIdx.x * 256 + threadIdx.x;
  const int k0 = blockIdx.y * KS;
  float su = 0.f, sv = 0.f;
  for (int k = k0; k < k0 + KS; ++k){
    float w = W[(size_t)k * H + n];
    su += g[k] * w;
    sv += beta[k] * w;
  }
  atomicAdd(&u[n], su);
  atomicAdd(&c[n], sv);
}

// ---- K4: Wt[n][k] = bf16( g[k] * W[k][n] ) ----
__global__ __launch_bounds__(256) void transpose_scale_kernel(
    const float* __restrict__ W, const float* __restrict__ g, u16* __restrict__ Wt,
    int D, int H)
{
  __shared__ u16 t[32][33];
  const int bx = blockIdx.x;  // n tile
  const int by = blockIdx.y;  // k tile
  const int x = threadIdx.x;  // 0..31
  const int y = threadIdx.y;  // 0..7
#pragma unroll
  for (int i = 0; i < 32; i += 8){
    int k = by * 32 + y + i;
    t[y + i][x] = f2bf(g[k] * W[(size_t)k * H + bx * 32 + x]);
  }
  __syncthreads();
#pragma unroll
  for (int i = 0; i < 32; i += 8)
    Wt[(size_t)(bx * 32 + y + i) * D + by * 32 + x] = t[x][y + i];
}

// ---- K5: bf16 MFMA GEMM (m97 structure: global_load_lds staging, 2-barrier loop),
//          LN folded into epilogue, + bias+GELU+residual (fp32 out) ----
#define BM 128
#define BN 128
#define BK 32

template<bool XB>
__global__ __launch_bounds__(256) void gemm_kernel(
    const float* __restrict__ Af,     // raw x fp32 (used when !XB)
    const u16*   __restrict__ Ab,     // x as bf16 (used when XB)
    const u16*   __restrict__ B,      // Wt bf16, N x K row-major
    const float2* __restrict__ stats, // per-row (mu, inv)
    const float* __restrict__ u,
    const float* __restrict__ c,
    float* __restrict__ out,          // M x N fp32
    int M, int N, int K)
{
  __shared__ __align__(16) u16 As[BM * BK];  // [m][k] linear
  __shared__ __align__(16) u16 Bs[BN * BK];  // [n][k] linear

  const int tid  = threadIdx.x;
  const int lane = tid & 63;
  const int w    = tid >> 6;
  const int wm   = w & 1;
  const int wn   = w >> 1;
  const int lr   = lane & 15;
  const int quad = lane >> 4;
  const int m0 = blockIdx.y * BM;
  const int n0 = blockIdx.x * BN;

  const int r0 = tid >> 2;           // tile row 0..63
  const int c0 = (tid & 3) * 8;      // k-chunk base
  const u16*   gB0 = B + (size_t)(n0 + r0) * K + c0;
  const u16*   gB1 = gB0 + (size_t)64 * K;
  u16* lA0 = &As[(size_t)tid * 8];          // byte off = tid*16 = wave base + lane*16
  u16* lA1 = &As[(size_t)(tid + 256) * 8];
  u16* lB0 = &Bs[(size_t)tid * 8];
  u16* lB1 = &Bs[(size_t)(tid + 256) * 8];

  const float* gAf0 = Af + (size_t)(m0 + r0) * K + c0;
  const float* gAf1 = gAf0 + (size_t)64 * K;
  const u16*   gAb0 = Ab + (size_t)(m0 + r0) * K + c0;
  const u16*   gAb1 = gAb0 + (size_t)64 * K;

  floatx4 acc[4][4] = {};

  for (int kt = 0; kt < K; kt += BK){
    uint4 a0, a1;
    if (!XB){
      // fp32 fallback: load+pack to regs while previous tile is still being consumed
      float4 p0 = *(const float4*)(gAf0 + kt);
      float4 p1 = *(const float4*)(gAf0 + kt + 4);
      float4 p2 = *(const float4*)(gAf1 + kt);
      float4 p3 = *(const float4*)(gAf1 + kt + 4);
      a0.x = pack2(p0.y, p0.x); a0.y = pack2(p0.w, p0.z);
      a0.z = pack2(p1.y, p1.x); a0.w = pack2(p1.w, p1.z);
      a1.x = pack2(p2.y, p2.x); a1.y = pack2(p2.w, p2.z);
      a1.z = pack2(p3.y, p3.x); a1.w = pack2(p3.w, p3.z);
    }

    __syncthreads();                       // prior tile fully consumed by ALL waves
    if (XB){
      gload16(lA0, gAb0 + kt);             // async global->LDS, 16B/lane
      gload16(lA1, gAb1 + kt);
    } else {
      *(uint4*)lA0 = a0; *(uint4*)lA1 = a1;
    }
    gload16(lB0, gB0 + kt);
    gload16(lB1, gB1 + kt);
    __syncthreads();                       // drains vmcnt(0)+lgkmcnt -> tile visible

    frag_ab af[4], bfr[4];
#pragma unroll
    for (int i = 0; i < 4; ++i)
      af[i] = *(const frag_ab*)&As[(wm * 64 + i * 16 + lr) * BK + quad * 8];
#pragma unroll
    for (int j = 0; j < 4; ++j)
      bfr[j] = *(const frag_ab*)&Bs[(wn * 64 + j * 16 + lr) * BK + quad * 8];
#pragma unroll
    for (int i = 0; i < 4; ++i)
#pragma unroll
      for (int j = 0; j < 4; ++j)
        acc[i][j] = __builtin_amdgcn_mfma_f32_16x16x32_bf16(af[i], bfr[j], acc[i][j], 0, 0, 0);
  }

  // epilogue. C/D layout: col = lane&15, row = quad*4 + reg
  float uj[4], cj[4];
#pragma unroll
  for (int j = 0; j < 4; ++j){
    const int col = n0 + wn * 64 + j * 16 + lr;
    uj[j] = u[col];
    cj[j] = c[col];
  }
#pragma unroll
  for (int i = 0; i < 4; ++i){
#pragma unroll
    for (int r = 0; r < 4; ++r){
      const int row = m0 + wm * 64 + i * 16 + quad * 4 + r;
      const float2 st = stats[row];          // (mu, inv)
      const float minv = -st.x * st.y;
      float* orow = out + (size_t)row * N;
#pragma unroll
      for (int j = 0; j < 4; ++j){
        const int col = n0 + wn * 64 + j * 16 + lr;
        float vv = st.y * acc[i][j][r] + minv * uj[j] + cj[j];
        float gl = 0.5f * vv * (1.0f + erff(vv * 0.70710678118654752f));
        float res = XB ? bf2f(Ab[(size_t)row * N + col])
                       : Af[(size_t)row * N + col];     // residual x (N==K here)
        orow[col] = gl + res;
      }
    }
  }
}

extern "C" void kernel_launch(void* const* d_in, const int* in_sizes, int n_in,
                              void* d_out, int out_size, void* d_ws, size_t ws_size,
                              hipStream_t stream) {
  const float* x     = (const float*)d_in[0];
  const float* gamma = (const float*)d_in[1];
  const float* beta  = (const float*)d_in[2];
  const float* W     = (const float*)d_in[3];
  const float* bias  = (const float*)d_in[4];
  float* out = (float*)d_out;

  const int D = in_sizes[1];            // 2048 (= K)
  const int H = in_sizes[4];            // 2048 (= N)
  const int M = in_sizes[0] / D;        // 32768

  // ws layout: stats(M*8) | u(H*4) | c(H*4) | Wt(H*D*2) | [xb(M*D*2) if it fits]
  float2* stats = (float2*)d_ws;
  float*  u     = (float*)(stats + M);
  float*  c     = u + H;
  u16*    Wt    = (u16*)(c + H);
  u16*    xb    = Wt + (size_t)H * D;
  size_t need_base = (size_t)M * 8 + (size_t)H * 8 + (size_t)H * D * 2;
  size_t need_xb   = need_base + (size_t)M * D * 2;
  const bool use_xb = (ws_size >= need_xb);

  if (use_xb)
    ln_stats_kernel<true ><<<M, D / 8, 0, stream>>>(x, stats, xb, D);
  else
    ln_stats_kernel<false><<<M, D / 8, 0, stream>>>(x, stats, xb, D);

  init_uc_kernel<<<(H + 255) / 256, 256, 0, stream>>>(bias, u, c, H);
  const int KS = 128;
  dim3 cg(H / 256, D / KS);
  colsum_kernel<<<cg, 256, 0, stream>>>(W, gamma, beta, u, c, D, H, KS);
  dim3 tb(32, 8), tg(H / 32, D / 32);
  transpose_scale_kernel<<<tg, tb, 0, stream>>>(W, gamma, Wt, D, H);

  dim3 gb(H / BN, M / BM);
  if (use_xb)
    gemm_kernel<true ><<<gb, 256, 0, stream>>>(x, xb, Wt, stats, u, c, out, M, H, D);
  else
    gemm_kernel<false><<<gb, 256, 0, stream>>>(x, xb, Wt, stats, u, c, out, M, H, D);
}

// Round 2
// 953.334 us; speedup vs baseline: 1.0197x; 1.0197x over previous
//
#include <hip/hip_runtime.h>
#include <math.h>

typedef unsigned short u16;
typedef unsigned int u32;
typedef __attribute__((ext_vector_type(8))) short frag_ab;   // 8 bf16 (4 VGPRs)
typedef __attribute__((ext_vector_type(4))) float floatx4;   // 4 fp32 acc

__device__ __forceinline__ u16 f2bf(float f){   // RNE fp32 -> bf16
  u32 u; __builtin_memcpy(&u, &f, 4);
  u32 r = u + 0x7fffu + ((u >> 16) & 1u);
  return (u16)(r >> 16);
}
__device__ __forceinline__ float bf2f(u16 h){
  u32 u = ((u32)h) << 16;
  float f; __builtin_memcpy(&f, &u, 4); return f;
}
// pack two fp32 -> two bf16 (truncation) in ONE v_perm: low u16 = trunc(lo), high = trunc(hi)
__device__ __forceinline__ u32 pack2(float hi, float lo){
  u32 a, b; __builtin_memcpy(&a, &hi, 4); __builtin_memcpy(&b, &lo, 4);
  return __builtin_amdgcn_perm(a, b, 0x07060302u);
}

// async global->LDS, 16B per lane. LDS dest must be wave-uniform base + lane*16,
// which our linear [row][chunk] layout with dest = base + tid*16 satisfies.
__device__ __forceinline__ void gload16(u16* l, const u16* g){
  __builtin_amdgcn_global_load_lds(
      (const __attribute__((address_space(1))) void*)g,
      (__attribute__((address_space(3))) void*)l, 16, 0, 0);
}

// branch-free GELU via Abramowitz-Stegun 7.1.26 erf (|eps| <= 1.5e-7).
// ~14 VALU ops incl. one v_exp_f32 + one v_rcp_f32; no divergence.
__device__ __forceinline__ float gelu_erf(float v){
  float z  = v * 0.70710678118654752f;
  float az = __builtin_fabsf(z);
  float t  = __builtin_amdgcn_rcpf(__builtin_fmaf(0.3275911f, az, 1.0f));
  float p  = __builtin_fmaf(t, 1.061405429f, -1.453152027f);
  p = __builtin_fmaf(p, t, 1.421413741f);
  p = __builtin_fmaf(p, t, -0.284496736f);
  p = __builtin_fmaf(p, t, 0.254829592f);
  p = p * t;
  float e  = __expf(-az * az);
  float er = __builtin_fmaf(-p, e, 1.0f);       // erf(|z|) = 1 - p*exp(-z^2)
  er = copysignf(er, z);
  return 0.5f * v * (1.0f + er);
}

// ---- K1: per-row LN stats, one WAVE per row (no LDS, no syncthreads).
// block = 256 (4 waves = 4 rows), grid = M/4. Coalesced float4 loads, uint2 bf16 stores.
template<bool XB>
__global__ __launch_bounds__(256) void ln_stats_kernel(
    const float* __restrict__ x, float2* __restrict__ stats,
    u16* __restrict__ xb, int D)
{
  const int wid  = threadIdx.x >> 6;
  const int lane = threadIdx.x & 63;
  const int row  = blockIdx.x * 4 + wid;
  const float* xr = x + (size_t)row * D;
  u16* xbr = xb + (size_t)row * D;

  float s = 0.f, q = 0.f;
  for (int base = lane * 4; base < D; base += 256){
    float4 a = *(const float4*)(xr + base);
    s += a.x + a.y + a.z + a.w;
    q = __builtin_fmaf(a.x, a.x, q);
    q = __builtin_fmaf(a.y, a.y, q);
    q = __builtin_fmaf(a.z, a.z, q);
    q = __builtin_fmaf(a.w, a.w, q);
    if (XB){
      u16 ov[4] = { f2bf(a.x), f2bf(a.y), f2bf(a.z), f2bf(a.w) };
      *(uint2*)(xbr + base) = *(const uint2*)ov;
    }
  }
#pragma unroll
  for (int o = 32; o > 0; o >>= 1){ s += __shfl_xor(s, o); q += __shfl_xor(q, o); }
  if (lane == 0){
    float invD = 1.0f / (float)D;
    float mu  = s * invD;
    float var = q * invD - mu * mu;
    stats[row] = make_float2(mu, rsqrtf(var + 1e-5f));
  }
}

// ---- K2: u[n]=0, c[n]=bias[n] ----
__global__ __launch_bounds__(256) void init_uc_kernel(
    const float* __restrict__ b, float* __restrict__ u, float* __restrict__ c, int H)
{
  int t = blockIdx.x * 256 + threadIdx.x;
  if (t < H){ u[t] = 0.f; c[t] = b[t]; }
}

// ---- K3: u[n] += sum_k g[k]W[k,n];  c[n] += sum_k beta[k]W[k,n]  (all fp32) ----
__global__ __launch_bounds__(256) void colsum_kernel(
    const float* __restrict__ W, const float* __restrict__ g, const float* __restrict__ beta,
    float* __restrict__ u, float* __restrict__ c, int D, int H, int KS)
{
  const int n  = blockIdx.x * 256 + threadIdx.x;
  const int k0 = blockIdx.y * KS;
  float su = 0.f, sv = 0.f;
  for (int k = k0; k < k0 + KS; ++k){
    float w = W[(size_t)k * H + n];
    su += g[k] * w;
    sv += beta[k] * w;
  }
  atomicAdd(&u[n], su);
  atomicAdd(&c[n], sv);
}

// ---- K4: Wt[n][k] = bf16( g[k] * W[k][n] ) ----
__global__ __launch_bounds__(256) void transpose_scale_kernel(
    const float* __restrict__ W, const float* __restrict__ g, u16* __restrict__ Wt,
    int D, int H)
{
  __shared__ u16 t[32][33];
  const int bx = blockIdx.x;  // n tile
  const int by = blockIdx.y;  // k tile
  const int x = threadIdx.x;  // 0..31
  const int y = threadIdx.y;  // 0..7
#pragma unroll
  for (int i = 0; i < 32; i += 8){
    int k = by * 32 + y + i;
    t[y + i][x] = f2bf(g[k] * W[(size_t)k * H + bx * 32 + x]);
  }
  __syncthreads();
#pragma unroll
  for (int i = 0; i < 32; i += 8)
    Wt[(size_t)(bx * 32 + y + i) * D + by * 32 + x] = t[x][y + i];
}

// ---- K5: bf16 MFMA GEMM. Double-buffered LDS (ONE barrier per K-step),
//          global_load_lds staging, bank-conflict-free XOR swizzle,
//          LN folded into epilogue, + bias + GELU(A&S erf) + residual.
//
// LDS swizzle (rule #21: both-sides-or-neither):
//   LDS[r][j] holds global chunk j ^ s(r), s(r) = (r>>1)&3 (16B chunks, 64B rows).
//   - stage: LDS dest stays LINEAR (tid*16, required by global_load_lds);
//            the per-lane GLOBAL source chunk is (tid&3) ^ s(tid>>2).
//   - read : fragment for (row m, quad) reads LDS chunk quad ^ s(m).
//   Balances each quad's 16 lanes across all 8 bank groups -> conflict-free b128.
#define BM 128
#define BN 128
#define BK 32

template<bool XB>
__global__ __launch_bounds__(256) void gemm_kernel(
    const float* __restrict__ Af,     // raw x fp32 (used when !XB)
    const u16*   __restrict__ Ab,     // x as bf16 (used when XB)
    const u16*   __restrict__ B,      // Wt bf16, N x K row-major
    const float2* __restrict__ stats, // per-row (mu, inv)
    const float* __restrict__ u,
    const float* __restrict__ c,
    float* __restrict__ out,          // M x N fp32
    int M, int N, int K)
{
  __shared__ __align__(16) u16 As[2][BM * BK];  // 2 x 8 KiB
  __shared__ __align__(16) u16 Bs[2][BN * BK];  // 2 x 8 KiB

  const int tid  = threadIdx.x;
  const int lane = tid & 63;
  const int w    = tid >> 6;
  const int wm   = w & 1;
  const int wn   = w >> 1;
  const int lr   = lane & 15;
  const int quad = lane >> 4;
  const int m0 = blockIdx.y * BM;
  const int n0 = blockIdx.x * BN;

  const int r0 = tid >> 2;                     // staged tile row 0..63
  const int cs = ((tid & 3) ^ ((r0 >> 1) & 3)) * 8;  // swizzled global chunk (elements)

  const u16* gB0 = B + (size_t)(n0 + r0) * K + cs;
  const u16* gB1 = gB0 + (size_t)64 * K;
  const float* gAf0 = Af + (size_t)(m0 + r0) * K + cs;
  const float* gAf1 = gAf0 + (size_t)64 * K;
  const u16*   gAb0 = Ab + (size_t)(m0 + r0) * K + cs;
  const u16*   gAb1 = gAb0 + (size_t)64 * K;

  // swizzled fragment read offsets (constant per thread)
  const int sread = (quad ^ ((lr >> 1) & 3)) * 8;

  floatx4 acc[4][4] = {};
  const int NT = K / BK;

  // ---- stage K-tile kt into buffer buf ----
  auto stage = [&](int buf, int kt){
    const int ko = kt * BK;
    if (XB){
      gload16(&As[buf][(size_t)tid * 8],         gAb0 + ko);
      gload16(&As[buf][(size_t)(tid + 256) * 8], gAb1 + ko);
    } else {
      float4 p0 = *(const float4*)(gAf0 + ko);
      float4 p1 = *(const float4*)(gAf0 + ko + 4);
      float4 p2 = *(const float4*)(gAf1 + ko);
      float4 p3 = *(const float4*)(gAf1 + ko + 4);
      uint4 a0, a1;
      a0.x = pack2(p0.y, p0.x); a0.y = pack2(p0.w, p0.z);
      a0.z = pack2(p1.y, p1.x); a0.w = pack2(p1.w, p1.z);
      a1.x = pack2(p2.y, p2.x); a1.y = pack2(p2.w, p2.z);
      a1.z = pack2(p3.y, p3.x); a1.w = pack2(p3.w, p3.z);
      *(uint4*)&As[buf][(size_t)tid * 8]         = a0;
      *(uint4*)&As[buf][(size_t)(tid + 256) * 8] = a1;
    }
    gload16(&Bs[buf][(size_t)tid * 8],         gB0 + ko);
    gload16(&Bs[buf][(size_t)(tid + 256) * 8], gB1 + ko);
  };

  stage(0, 0);
  __syncthreads();                              // implicit vmcnt(0)+lgkmcnt(0) drain

  for (int kt = 0; kt < NT; ++kt){
    const int cur = kt & 1;
    if (kt + 1 < NT) stage(cur ^ 1, kt + 1);    // issue next tile BEFORE compute

    frag_ab af[4], bfr[4];
#pragma unroll
    for (int i = 0; i < 4; ++i)
      af[i] = *(const frag_ab*)&As[cur][(wm * 64 + i * 16 + lr) * BK + sread];
#pragma unroll
    for (int j = 0; j < 4; ++j)
      bfr[j] = *(const frag_ab*)&Bs[cur][(wn * 64 + j * 16 + lr) * BK + sread];
#pragma unroll
    for (int i = 0; i < 4; ++i)
#pragma unroll
      for (int j = 0; j < 4; ++j)
        acc[i][j] = __builtin_amdgcn_mfma_f32_16x16x32_bf16(af[i], bfr[j], acc[i][j], 0, 0, 0);

    __syncthreads();   // drains vmcnt(0): staged buf^1 landed; all waves done with buf[cur]
  }

  // epilogue. C/D layout: col = lane&15, row = quad*4 + reg
  float uj[4], cj[4];
#pragma unroll
  for (int j = 0; j < 4; ++j){
    const int col = n0 + wn * 64 + j * 16 + lr;
    uj[j] = u[col];
    cj[j] = c[col];
  }
#pragma unroll
  for (int i = 0; i < 4; ++i){
#pragma unroll
    for (int r = 0; r < 4; ++r){
      const int row = m0 + wm * 64 + i * 16 + quad * 4 + r;
      const float2 st = stats[row];          // (mu, inv)
      const float minv = -st.x * st.y;
      float* orow = out + (size_t)row * N;
#pragma unroll
      for (int j = 0; j < 4; ++j){
        const int col = n0 + wn * 64 + j * 16 + lr;
        float vv = st.y * acc[i][j][r] + minv * uj[j] + cj[j];
        float gl = gelu_erf(vv);
        float res = XB ? bf2f(Ab[(size_t)row * N + col])
                       : Af[(size_t)row * N + col];     // residual x (N==K here)
        orow[col] = gl + res;
      }
    }
  }
}

extern "C" void kernel_launch(void* const* d_in, const int* in_sizes, int n_in,
                              void* d_out, int out_size, void* d_ws, size_t ws_size,
                              hipStream_t stream) {
  const float* x     = (const float*)d_in[0];
  const float* gamma = (const float*)d_in[1];
  const float* beta  = (const float*)d_in[2];
  const float* W     = (const float*)d_in[3];
  const float* bias  = (const float*)d_in[4];
  float* out = (float*)d_out;

  const int D = in_sizes[1];            // 2048 (= K)
  const int H = in_sizes[4];            // 2048 (= N)
  const int M = in_sizes[0] / D;        // 32768

  // ws layout: stats(M*8) | u(H*4) | c(H*4) | Wt(H*D*2) | [xb(M*D*2) if it fits]
  float2* stats = (float2*)d_ws;
  float*  u     = (float*)(stats + M);
  float*  c     = u + H;
  u16*    Wt    = (u16*)(c + H);
  u16*    xb    = Wt + (size_t)H * D;
  size_t need_base = (size_t)M * 8 + (size_t)H * 8 + (size_t)H * D * 2;
  size_t need_xb   = need_base + (size_t)M * D * 2;
  const bool use_xb = (ws_size >= need_xb);

  if (use_xb)
    ln_stats_kernel<true ><<<M / 4, 256, 0, stream>>>(x, stats, xb, D);
  else
    ln_stats_kernel<false><<<M / 4, 256, 0, stream>>>(x, stats, xb, D);

  init_uc_kernel<<<(H + 255) / 256, 256, 0, stream>>>(bias, u, c, H);
  const int KS = 128;
  dim3 cg(H / 256, D / KS);
  colsum_kernel<<<cg, 256, 0, stream>>>(W, gamma, beta, u, c, D, H, KS);
  dim3 tb(32, 8), tg(H / 32, D / 32);
  transpose_scale_kernel<<<tg, tb, 0, stream>>>(W, gamma, Wt, D, H);

  dim3 gb(H / BN, M / BM);
  if (use_xb)
    gemm_kernel<true ><<<gb, 256, 0, stream>>>(x, xb, Wt, stats, u, c, out, M, H, D);
  else
    gemm_kernel<false><<<gb, 256, 0, stream>>>(x, xb, Wt, stats, u, c, out, M, H, D);
}